// Round 5
// baseline (173.143 us; speedup 1.0000x reference)
//
#include <hip/hip_runtime.h>
#include <math.h>

typedef __bf16 bf16x8 __attribute__((ext_vector_type(8)));
typedef __bf16 bf16x4 __attribute__((ext_vector_type(4)));
typedef float  f32x4  __attribute__((ext_vector_type(4)));

namespace {
constexpr int L_ = 512, D_ = 512, NF = 11;
constexpr long WE = (long)L_ * L_;   // 262144 elems, one 512x512 plane
constexpr long NE = 8 * WE;          // 2097152 elems, B*L*D
constexpr long CPL = 512L * 1024;    // concatenated plane (512 rows x 1024)
constexpr float NEGV = -1.0e9f;
constexpr float INV_TEMP = 0.044194173824159216f; // 1/sqrt(512)
}

typedef __attribute__((address_space(1))) void gv_t;
typedef __attribute__((address_space(3))) void lv_t;

__device__ __forceinline__ void async_cp16(const void* g, void* l) {
  __builtin_amdgcn_global_load_lds((gv_t*)g, (lv_t*)l, 16, 0, 0);
}

// ======== NT GEMM core: BM x BN tile, BK=64, counted-vmcnt pipeline (T3+T4) ==
// LDS per buffer: [rows][64] bf16 (128B rows), 16B slots XOR-swizzled by
// (row&7); global_load_lds dest lane-linear, source col pre-swizzled, read
// applies same XOR -> conflict-free ds_read_b128.
// Schedule per K-step (raw s_barrier, NO vmcnt(0) drain in main loop):
//   stage(next); s_waitcnt vmcnt(LOADS) // waits only PREV step's loads
//   s_barrier ; MFMA(cur) ; s_barrier
template<int BM, int BN>
__device__ __forceinline__ void nt_db(const __bf16* __restrict__ A,
                                      const __bf16* __restrict__ B,
                                      const int K, const int m0, const int n0,
                                      char* smem, f32x4 (&acc)[BM / 32][BN / 32])
{
  constexpr int MI = BM / 32, NJ = BN / 32;
  constexpr int LOADS = MI + NJ;              // per-thread loads per stage
  constexpr int ABUF = BM * 64;
  constexpr int BBUF = BN * 64;
  __bf16* sA = (__bf16*)smem;
  __bf16* sB = sA + 2 * ABUF;
  const int tid = threadIdx.x;
  const int w = tid >> 6, l = tid & 63;
  const int quad = l >> 4, l16 = l & 15;
  const int wm = (w >> 1) * (BM / 2), wn = (w & 1) * (BN / 2);
  const int lr = l >> 3;                      // row within 8-row chunk
  const int sc = ((l & 7) ^ lr) << 3;         // swizzled source col (elems)
  const __bf16* gA = A + (long)(m0 + lr) * K + sc;
  const __bf16* gB = B + (long)(n0 + lr) * K + sc;
  const int xo = (l16 & 7) << 4;              // read-side XOR (bytes)

  auto stage = [&](int buf, int k0) {
    char* dA = (char*)(sA + buf * ABUF) + l * 16;
    char* dB = (char*)(sB + buf * BBUF) + l * 16;
    #pragma unroll
    for (int ci = 0; ci < MI; ++ci) {
      const int qi = ci * 4 + w;
      async_cp16(gA + (long)(qi * 8) * K + k0, dA + qi * 1024);
    }
    #pragma unroll
    for (int ci = 0; ci < NJ; ++ci) {
      const int qi = ci * 4 + w;
      async_cp16(gB + (long)(qi * 8) * K + k0, dB + qi * 1024);
    }
  };
  auto compute = [&](int buf) {
    const char* bA = (const char*)(sA + buf * ABUF);
    const char* bB = (const char*)(sB + buf * BBUF);
    #pragma unroll
    for (int p = 0; p < 2; ++p) {
      bf16x8 af[MI], bfr[NJ];
      #pragma unroll
      for (int i = 0; i < MI; ++i)
        af[i] = *(const bf16x8*)(bA + (wm + i * 16 + l16) * 128
                                 + ((p * 64 + quad * 16) ^ xo));
      #pragma unroll
      for (int j = 0; j < NJ; ++j)
        bfr[j] = *(const bf16x8*)(bB + (wn + j * 16 + l16) * 128
                                  + ((p * 64 + quad * 16) ^ xo));
      __builtin_amdgcn_s_setprio(1);
      #pragma unroll
      for (int i = 0; i < MI; ++i)
        #pragma unroll
        for (int j = 0; j < NJ; ++j)
          acc[i][j] = __builtin_amdgcn_mfma_f32_16x16x32_bf16(af[i], bfr[j], acc[i][j], 0, 0, 0);
      __builtin_amdgcn_s_setprio(0);
    }
  };

  stage(0, 0);
  int cur = 0;
  const int NS = K >> 6;
  for (int s = 0; s < NS; ++s) {
    if (s + 1 < NS) {
      stage(cur ^ 1, (s + 1) << 6);
      asm volatile("s_waitcnt vmcnt(%0)" :: "n"(LOADS) : "memory");
    } else {
      asm volatile("s_waitcnt vmcnt(0)" ::: "memory");
    }
    __builtin_amdgcn_sched_barrier(0);
    __builtin_amdgcn_s_barrier();             // cur buffer fully staged
    compute(cur);
    __builtin_amdgcn_s_barrier();             // all reads of cur done
    cur ^= 1;
  }
  __builtin_amdgcn_sched_barrier(0);          // keep epilogue below barriers
}

// ======== k1: pure bf16 conversion of q,k,v + 6 weights (896 blocks) ========
__global__ __launch_bounds__(256)
void cvt_kernel(const float* __restrict__ q, const float* __restrict__ k,
                const float* __restrict__ v,
                const float* __restrict__ Wq, const float* __restrict__ Wk,
                const float* __restrict__ Wqf, const float* __restrict__ Wkf,
                const float* __restrict__ Wv, const float* __restrict__ Wfc,
                __bf16* __restrict__ qb, __bf16* __restrict__ kb,
                __bf16* __restrict__ vb, __bf16* __restrict__ wb)
{
  constexpr long QC8 = 262144;              // 8-elem granules per q/k/v (2^18)
  constexpr long WC8 = 32768;               // granules per weight (2^15)
  constexpr long TOT8 = 3 * QC8 + 6 * WC8;  // 983040
  const float* srcs[9] = {q, k, v, Wq, Wk, Wqf, Wkf, Wv, Wfc};
  __bf16* dsts[9] = {qb, kb, vb, wb, wb + WE, wb + 2 * WE,
                     wb + 3 * WE, wb + 4 * WE, wb + 5 * WE};
  for (long t = (long)blockIdx.x * 256 + threadIdx.x; t < TOT8; t += 896L * 256) {
    int ti; long off;
    if (t < 3 * QC8) { ti = (int)(t >> 18); off = t & (QC8 - 1); }
    else { long u = t - 3 * QC8; ti = 3 + (int)(u >> 15); off = u & (WC8 - 1); }
    const float4 f0 = ((const float4*)srcs[ti])[off * 2];
    const float4 f1 = ((const float4*)srcs[ti])[off * 2 + 1];
    bf16x8 o;
    o[0] = (__bf16)f0.x; o[1] = (__bf16)f0.y; o[2] = (__bf16)f0.z; o[3] = (__bf16)f0.w;
    o[4] = (__bf16)f1.x; o[5] = (__bf16)f1.y; o[6] = (__bf16)f1.z; o[7] = (__bf16)f1.w;
    ((bf16x8*)dsts[ti])[off] = o;
  }
}

// ======== k2: 5 projections (fid<640) + feature softmax (fid>=640) ========
// GEMM: 128x128 tiles, XCD-swizzled. Feat blocks fill proj's tail round.
__global__ __launch_bounds__(256)
void projfeat_kernel(const __bf16* __restrict__ qb, const __bf16* __restrict__ kb,
                     const __bf16* __restrict__ vb, const __bf16* __restrict__ wb,
                     const float* __restrict__ x, const float* __restrict__ imp,
                     const int* __restrict__ lens,
                     __bf16* __restrict__ qcat, __bf16* __restrict__ kcat,
                     __bf16* __restrict__ qfkfT, __bf16* __restrict__ vpb,
                     __bf16* __restrict__ featb)
{
  __shared__ __align__(16) char smem[65536];  // 64 KB -> 2 blocks/CU
  const int fid = blockIdx.x;
  const int tid = threadIdx.x;
  const int w = tid >> 6, l = tid & 63;

  if (fid < 640) {
    const int xcd = fid & 7, g = fid >> 3;    // 640 = 8 * 80
    const int z = g >> 4, r = g & 15;         // z: 0 Wq, 1 Wk, 2 Wqf, 3 Wkf, 4 Wv
    const int n0 = (r & 3) * 128;
    const int m0 = (((r >> 2) << 3) + xcd) * 128;
    const __bf16* A = (z == 0 || z == 2) ? qb : (z == 4 ? vb : kb);
    const __bf16* B = wb + (long)z * WE;
    f32x4 acc[4][4];
    #pragma unroll
    for (int i = 0; i < 4; ++i)
      #pragma unroll
      for (int j = 0; j < 4; ++j) acc[i][j] = 0.0f;
    nt_db<128, 128>(A, B, 512, m0, n0, smem, acc);

    const int quad = l >> 4, l16 = l & 15;
    const int wm = (w >> 1) * 64, wn = (w & 1) * 64;
    #pragma unroll
    for (int i = 0; i < 4; ++i) {
      const int mb = m0 + wm + i * 16 + quad * 4;
      #pragma unroll
      for (int j = 0; j < 4; ++j) {
        const int nn = n0 + wn + j * 16 + l16;
        f32x4 c = acc[i][j];
        if (z < 2) {
          __bf16* C = (z == 0) ? qcat : kcat;
          #pragma unroll
          for (int r2 = 0; r2 < 4; ++r2)
            C[(long)(mb + r2) * 1024 + nn] = (__bf16)c[r2];
        } else if (z == 4) {
          #pragma unroll
          for (int r2 = 0; r2 < 4; ++r2)
            vpb[(long)(mb + r2) * 512 + nn] = (__bf16)c[r2];
        } else {                               // qf/kf written transposed
          __bf16* T = qfkfT + (long)(z - 2) * NE;
          const long bb = (long)(mb >> 9) << 18;
          const int li = mb & 511;
          bf16x4 pk;
          pk[0] = (__bf16)c[0]; pk[1] = (__bf16)c[1];
          pk[2] = (__bf16)c[2]; pk[3] = (__bf16)c[3];
          *(bf16x4*)(T + bb + (long)nn * 512 + li) = pk;
        }
      }
    }
    return;
  }

  // ---- feature softmax (proven path), blocks 640..767 ----
  float* xfs = (float*)smem;                  // 22.5 KB
  const int flat = fid - 640;
  const int b = flat >> 4;
  const int i0 = (flat & 15) * 32;
  for (int idx = tid; idx < L_ * NF; idx += 256) {
    int j = idx / NF, f = idx - j * NF;
    xfs[idx] = x[((long)b * L_ + j) * D_ + f];
  }
  float im[NF];
  #pragma unroll
  for (int f = 0; f < NF; ++f) im[f] = imp[f];
  const int len = lens[b];
  __syncthreads();
  for (int r = 0; r < 8; ++r) {
    const int i = i0 + w * 8 + r;
    float xi[NF];
    #pragma unroll
    for (int f = 0; f < NF; ++f) xi[f] = xfs[i * NF + f];
    float lv[8];
    float m = -INFINITY;
    #pragma unroll
    for (int t = 0; t < 8; ++t) {
      int j = l + t * 64;
      float s = 0.f;
      #pragma unroll
      for (int f = 0; f < NF; ++f) s = fmaf(fabsf(xi[f] - xfs[j * NF + f]), im[f], s);
      s = (j < len) ? s : NEGV;
      lv[t] = s;
      m = fmaxf(m, s);
    }
    #pragma unroll
    for (int o = 32; o >= 1; o >>= 1) m = fmaxf(m, __shfl_xor(m, o));
    float ssum = 0.f;
    #pragma unroll
    for (int t = 0; t < 8; ++t) { lv[t] = expf(lv[t] - m); ssum += lv[t]; }
    #pragma unroll
    for (int o = 32; o >= 1; o >>= 1) ssum += __shfl_xor(ssum, o);
    float inv = 1.0f / ssum;
    #pragma unroll
    for (int t = 0; t < 8; ++t)
      featb[((long)b * L_ + i) * L_ + l + t * 64] = (__bf16)(lv[t] * inv);
  }
}

// ======== k3: qf2 -> qcat[:,512:], kf2 -> kcat[:,512:], vp2T (384 blocks) ====
__global__ __launch_bounds__(256)
void mega2_kernel(const __bf16* __restrict__ featb, const __bf16* __restrict__ qfkfT,
                  const __bf16* __restrict__ wb, const __bf16* __restrict__ vpb,
                  __bf16* __restrict__ qcat, __bf16* __restrict__ kcat,
                  __bf16* __restrict__ vp2T)
{
  __shared__ __align__(16) char smem[65536];
  const int id = blockIdx.x;
  const int xcd = id & 7, g = id >> 3;        // 384 = 8 * 48
  const int z = g >> 1;                       // 0..23
  const int t = (g & 1) * 8 + xcd;            // tile 0..15
  const int m0 = (t >> 2) * 128, n0 = (t & 3) * 128;
  const __bf16* A; const __bf16* B; __bf16* C; int ldc;
  if (z < 16) {
    const int b = z & 7, s = z >> 3;
    A = featb + (long)b * WE;
    B = qfkfT + (long)s * NE + (long)b * WE;
    C = (s ? kcat : qcat) + (long)b * CPL + 512;
    ldc = 1024;
  } else {
    const int b = z - 16;
    A = wb + 5 * WE;                          // Wfc (swapped operands -> vp2T)
    B = vpb + (long)b * WE;
    C = vp2T + (long)b * WE;
    ldc = 512;
  }
  f32x4 acc[4][4];
  #pragma unroll
  for (int i = 0; i < 4; ++i)
    #pragma unroll
    for (int j = 0; j < 4; ++j) acc[i][j] = 0.0f;
  nt_db<128, 128>(A, B, 512, m0, n0, smem, acc);

  const int tid = threadIdx.x, w = tid >> 6, l = tid & 63;
  const int quad = l >> 4, l16 = l & 15;
  const int wm = (w >> 1) * 64, wn = (w & 1) * 64;
  #pragma unroll
  for (int i = 0; i < 4; ++i) {
    const int mb = m0 + wm + i * 16 + quad * 4;
    #pragma unroll
    for (int j = 0; j < 4; ++j) {
      const int nn = n0 + wn + j * 16 + l16;
      f32x4 c = acc[i][j];
      #pragma unroll
      for (int r2 = 0; r2 < 4; ++r2)
        C[(long)(mb + r2) * ldc + nn] = (__bf16)c[r2];
    }
  }
}

// ======== k4: attn = tanh(mask(qcat.kcat^T/temp)), 64x64 tiles, 512 blocks ===
__global__ __launch_bounds__(256)
void scores_kernel(const __bf16* __restrict__ qcat, const __bf16* __restrict__ kcat,
                   const int* __restrict__ lens, float* __restrict__ attnf,
                   __bf16* __restrict__ attnb)
{
  __shared__ __align__(16) char smem[32768];  // 32 KB
  const int id = blockIdx.x;                  // 512 = 8 b * 64 tiles
  const int b = id & 7, g = id >> 3;          // one b per XCD -> L2-resident
  const int m0 = (g >> 3) * 64, n0 = (g & 7) * 64;
  const int len = lens[b];
  f32x4 acc[2][2];
  #pragma unroll
  for (int i = 0; i < 2; ++i)
    #pragma unroll
    for (int j = 0; j < 2; ++j) acc[i][j] = 0.0f;
  nt_db<64, 64>(qcat + (long)b * CPL, kcat + (long)b * CPL, 1024, m0, n0, smem, acc);

  const long off = (long)b * WE;
  const int tid = threadIdx.x, w = tid >> 6, l = tid & 63;
  const int quad = l >> 4, l16 = l & 15;
  const int wm = (w >> 1) * 32, wn = (w & 1) * 32;
  #pragma unroll
  for (int i = 0; i < 2; ++i) {
    const int mb = m0 + wm + i * 16 + quad * 4;
    #pragma unroll
    for (int j = 0; j < 2; ++j) {
      const int nn = n0 + wn + j * 16 + l16;
      f32x4 c = acc[i][j];
      #pragma unroll
      for (int r2 = 0; r2 < 4; ++r2) {
        float vv = c[r2] * INV_TEMP;
        vv = (nn < len) ? tanhf(vv) : 0.0f;
        attnf[off + (long)(mb + r2) * 512 + nn] = vv;
        attnb[off + (long)(mb + r2) * 512 + nn] = (__bf16)vv;
      }
    }
  }
}

// ======== k5: out = LN(attn @ vp2 + q) fused, 16 rows x 512 cols, 256 blocks =
// BK=32 counted-vmcnt double-buffer; B LDS rows are 64B (4x16B slots),
// XOR-swizzled by (row&3) (cuts 8-way conflict to 4-way on ds_read_b128).
__global__ __launch_bounds__(256)
void av2ln_kernel(const __bf16* __restrict__ attnb, const __bf16* __restrict__ vp2T,
                  const float* __restrict__ q, const float* __restrict__ gamma,
                  const float* __restrict__ beta, float* __restrict__ outp)
{
  __shared__ __align__(16) __bf16 sA[2 * 16 * 32];    // 2 KB
  __shared__ __align__(16) __bf16 sB[2 * 512 * 32];   // 64 KB
  __shared__ float lnbuf[4][16][2];
  __shared__ float lnmv[16][2];
  const int bid = blockIdx.x;
  const int b = bid & 7;                      // XCD affinity for plane b
  const int m0 = (bid >> 3) * 16;
  const int tid = threadIdx.x;
  const int w = tid >> 6, l = tid & 63;
  const int quad = l >> 4, l16 = l & 15;
  const long aoff = (long)b * WE;

  const int sr = l >> 2;                      // row within 16-row chunk
  const int scs = (((l & 3) ^ (sr & 3)) << 3);  // swizzled source col (elems)
  const int xo4 = (l16 & 3) << 4;             // read-side XOR (bytes)

  f32x4 acc[8];
  #pragma unroll
  for (int j = 0; j < 8; ++j) acc[j] = 0.0f;

  auto stage = [&](int buf, int k0) {
    char* dB = (char*)(sB + buf * (512 * 32)) + l * 16;
    #pragma unroll
    for (int it = 0; it < 8; ++it) {          // B: 32 chunks of 16 rows
      const int chunk = it * 4 + w;
      const int d = chunk * 16 + sr;
      async_cp16(vp2T + aoff + (long)d * 512 + k0 + scs, dB + chunk * 1024);
    }
    if (w == 0) {                             // A: 16 rows x 32 cols (1 KB)
      char* dA = (char*)(sA + buf * (16 * 32)) + l * 16;
      async_cp16(attnb + aoff + (long)(m0 + sr) * 512 + k0 + scs, dA);
    }
  };
  auto compute = [&](int buf) {
    const char* bA = (const char*)(sA + buf * (16 * 32));
    const char* bB = (const char*)(sB + buf * (512 * 32));
    bf16x8 af = *(const bf16x8*)(bA + l16 * 64 + ((quad << 4) ^ xo4));
    __builtin_amdgcn_s_setprio(1);
    #pragma unroll
    for (int j = 0; j < 8; ++j) {
      bf16x8 bfr = *(const bf16x8*)(bB + (w * 128 + j * 16 + l16) * 64
                                    + ((quad << 4) ^ xo4));
      acc[j] = __builtin_amdgcn_mfma_f32_16x16x32_bf16(af, bfr, acc[j], 0, 0, 0);
    }
    __builtin_amdgcn_s_setprio(0);
  };

  stage(0, 0);
  int cur = 0;
  for (int s = 0; s < 16; ++s) {
    if (s + 1 < 16) {
      stage(cur ^ 1, (s + 1) * 32);
      if (w == 0) asm volatile("s_waitcnt vmcnt(9)" ::: "memory");
      else        asm volatile("s_waitcnt vmcnt(8)" ::: "memory");
    } else {
      asm volatile("s_waitcnt vmcnt(0)" ::: "memory");
    }
    __builtin_amdgcn_sched_barrier(0);
    __builtin_amdgcn_s_barrier();             // cur buffer fully staged
    compute(cur);
    __builtin_amdgcn_s_barrier();             // all reads of cur done
    cur ^= 1;
  }
  __builtin_amdgcn_sched_barrier(0);

  // residual + row sums (rows quad*4+r), then LN (proven round-0 epilogue)
  float uval[8][4];
  float sm[4] = {0.f, 0.f, 0.f, 0.f}, ss[4] = {0.f, 0.f, 0.f, 0.f};
  #pragma unroll
  for (int r = 0; r < 4; ++r) {
    const long row = (long)b * 512 + m0 + quad * 4 + r;
    #pragma unroll
    for (int j = 0; j < 8; ++j) {
      const int col = w * 128 + j * 16 + l16;
      float u = acc[j][r] + q[row * 512 + col];
      uval[j][r] = u;
      sm[r] += u;
      ss[r] = fmaf(u, u, ss[r]);
    }
  }
  #pragma unroll
  for (int o = 1; o <= 8; o <<= 1) {          // reduce across 16 lanes of quad
    #pragma unroll
    for (int r = 0; r < 4; ++r) { sm[r] += __shfl_xor(sm[r], o); ss[r] += __shfl_xor(ss[r], o); }
  }
  if (l16 == 0) {
    #pragma unroll
    for (int r = 0; r < 4; ++r) {
      lnbuf[w][quad * 4 + r][0] = sm[r];
      lnbuf[w][quad * 4 + r][1] = ss[r];
    }
  }
  __syncthreads();
  if (tid < 16) {
    float S = 0.f, SS = 0.f;
    #pragma unroll
    for (int w2 = 0; w2 < 4; ++w2) { S += lnbuf[w2][tid][0]; SS += lnbuf[w2][tid][1]; }
    const float mu = S * (1.0f / 512.0f);
    const float var = SS * (1.0f / 512.0f) - mu * mu;
    lnmv[tid][0] = mu;
    lnmv[tid][1] = 1.0f / sqrtf(var + 1e-6f);
  }
  __syncthreads();
  #pragma unroll
  for (int r = 0; r < 4; ++r) {
    const int rr = quad * 4 + r;
    const float mu = lnmv[rr][0], inv = lnmv[rr][1];
    const long row = (long)b * 512 + m0 + rr;
    #pragma unroll
    for (int j = 0; j < 8; ++j) {
      const int col = w * 128 + j * 16 + l16;
      outp[row * 512 + col] = (uval[j][r] - mu) * inv * gamma[col] + beta[col];
    }
  }
}

extern "C" void kernel_launch(void* const* d_in, const int* in_sizes, int n_in,
                              void* d_out, int out_size, void* d_ws, size_t ws_size,
                              hipStream_t stream) {
    const float* q     = (const float*)d_in[0];
    const float* k     = (const float*)d_in[1];
    const float* v     = (const float*)d_in[2];
    const float* x     = (const float*)d_in[3];
    const int*   lens  = (const int*)d_in[4];
    const float* Wq    = (const float*)d_in[5];
    const float* Wk    = (const float*)d_in[6];
    const float* Wv    = (const float*)d_in[7];
    const float* Wqf   = (const float*)d_in[8];
    const float* Wkf   = (const float*)d_in[9];
    const float* Wfc   = (const float*)d_in[10];
    const float* imp   = (const float*)d_in[11];
    const float* gamma = (const float*)d_in[12];
    const float* beta  = (const float*)d_in[13];

    constexpr long MB = 1 << 20;
    char* w = (char*)d_ws;
    __bf16* qfkfT = (__bf16*)(w);            //  0.. 8MB : qfT,kfT (transposed)
    __bf16* vpb   = (__bf16*)(w + 8 * MB);   //  8..12MB : vp
    __bf16* vp2T  = (__bf16*)(w + 12 * MB);  // 12..16MB : vp2T
    __bf16* qcat  = (__bf16*)(w + 16 * MB);  // 16..24MB : [qp | qf2] K=1024
    __bf16* kcat  = (__bf16*)(w + 24 * MB);  // 24..32MB : [kp | kf2]
    __bf16* featb = (__bf16*)(w + 32 * MB);  // 32..36MB : feat_attn bf16
    __bf16* attnb = (__bf16*)(w + 36 * MB);  // 36..40MB : attn bf16

    float*  outp  = (float*)d_out;           // output 0 [B,L,D]
    float*  attnf = outp + NE;               // output 1 [B,L,L]

    // bf16 scratch in d_out: qb/kb (outp region) dead after k2; vb/wb (attnf
    // region) dead after k3; attnf written k4, outp written k5.
    __bf16* qb = (__bf16*)d_out;             //  0.. 4MB of d_out
    __bf16* kb = qb + NE;                    //  4.. 8MB
    __bf16* vb = kb + NE;                    //  8..12MB
    __bf16* wb = vb + NE;                    // 12..15MB : Wq,Wk,Wqf,Wkf,Wv,Wfc

    // 1) bf16 conversion of q,k,v + weights (896 blocks)
    cvt_kernel<<<dim3(896), 256, 0, stream>>>(q, k, v, Wq, Wk, Wqf, Wkf, Wv, Wfc,
                                              qb, kb, vb, wb);

    // 2) 5 projections (640) + feature softmax (128) = 768 blocks
    projfeat_kernel<<<dim3(768), 256, 0, stream>>>(qb, kb, vb, wb, x, imp, lens,
                                                   qcat, kcat, qfkfT, vpb, featb);

    // 3) qf2,kf2 -> cat right halves + vp2T = NT(Wfc, vp) (384 blocks)
    mega2_kernel<<<dim3(384), 256, 0, stream>>>(featb, qfkfT, wb, vpb,
                                                qcat, kcat, vp2T);

    // 4) attn = tanh(mask(qcat.kcat^T / temp)), K=1024 (512 blocks, 64x64)
    scores_kernel<<<dim3(512), 256, 0, stream>>>(qcat, kcat, lens, attnf, attnb);

    // 5) out = LN(attn @ vp2 + q) fused (256 blocks, full-row)
    av2ln_kernel<<<dim3(256), 256, 0, stream>>>(attnb, vp2T, q, gamma, beta, outp);
}